// Round 11
// baseline (212.213 us; speedup 1.0000x reference)
//
#include <hip/hip_runtime.h>

// VersorRotorRNN: B=16, S=256, N=16, D=6, H=16, 32 blades (Cl(5,0)).
// Segmented parallel scan over S (SEGT=64, L=4) + CENTER SPLIT:
// Cl(5,0) = P+Cl (+) P-Cl via central idempotents P± = (1±w)/2, w=e12345.
// Each eigenspace is 16-dim; compact even-blade coords XOR, so one GP =
// two 16x16 signed XOR-convs = 512 FMA. Butterfly folded into k_prep'd
// weights. |a|^2_blades = (S+ + S-)/2.
//
// R2+R4: never min-waves>=2; here VGPR MUST be <=128 (1024-thr block).
// R5: no per-thread LDS weight reads -> wave-uniform scalar loads.
// R7/R8: never #pragma unroll the outer step loops (I$ bloat).
// R9/R10: fused seg+scan+apply; center split. VALUBusy 74% @ 82.7us.
// R11: block = 16 waves = all 16 h of ONE chain (SEGT=64, scan width 64);
//   h-reduction in LDS; out written in-kernel. WS2 (48MB round-trip) and
//   k_reduce eliminated; 16 waves/CU.

#define EPS 1e-8f

constexpr int pcnt(int v) { int s = 0; while (v) { s += v & 1; v >>= 1; } return s; }
constexpr float sgnf(int a, int b) {
    a >>= 1; int s = 0;
    while (a) { s += pcnt(a & b); a >>= 1; }
    return (s & 1) ? -1.0f : 1.0f;
}
struct Tab16 {
    float sg2[16][16];  // sgn(m(c1), m(c2)) : compact-index Cayley signs
    float sig[16];      // sgn(m(c)^31, 31)  : odd-partner collapse sign
    int   cm[16];       // compact -> even blade mask (bit4 = parity(low4))
};
constexpr Tab16 make16() {
    Tab16 t{};
    for (int c = 0; c < 16; ++c) {
        int m = c | ((pcnt(c) & 1) << 4);
        t.cm[c] = m;
        t.sig[c] = sgnf(m ^ 31, 31);
    }
    for (int i = 0; i < 16; ++i)
        for (int j = 0; j < 16; ++j)
            t.sg2[i][j] = sgnf(t.cm[i], t.cm[j]);
    return t;
}
__device__ constexpr Tab16 T16 = make16();

// ---- prep: eigen-transform W_in/b_in per (h, sign) ----
// WP layout per h (224 floats): [sign(2)][ d(6)*16 + c | 96 + c(bias) ]
__global__ __launch_bounds__(256, 1) void k_prep(
        const float* __restrict__ W_in, const float* __restrict__ b_in,
        float* __restrict__ WP) {
    const int idx = blockIdx.x * 256 + threadIdx.x;
    if (idx >= 16 * 224) return;
    const int h = idx / 224, r = idx % 224;
    const int sg = r / 112, r2 = r % 112;
    const float pm = sg ? -1.0f : 1.0f;
    float val;
    if (r2 < 96) {
        const int d = r2 >> 4, c = r2 & 15, m = T16.cm[c];
        val = W_in[d * 512 + h * 32 + m]
            + pm * T16.sig[c] * W_in[d * 512 + h * 32 + (m ^ 31)];
    } else {
        const int c = r2 - 96, m = T16.cm[c];
        val = b_in[h * 32 + m] + pm * T16.sig[c] * b_in[h * 32 + (m ^ 31)];
    }
    WP[idx] = val;
}

// U[c] = bias±[c] + sum_d xv[d]*W±[d][c]  (+1 on c=0: scalar -> both signs)
__device__ __forceinline__ void build_u16(const float* __restrict__ Wsp,
                                          const float xv[6], float U[16]) {
#pragma unroll
    for (int c = 0; c < 16; ++c) U[c] = Wsp[96 + c];
#pragma unroll
    for (int d = 0; d < 6; ++d)
#pragma unroll
        for (int c = 0; c < 16; ++c)
            U[c] = fmaf(xv[d], Wsp[d * 16 + c], U[c]);
    U[0] += 1.0f;  // delta_r's +1 (scalar blade lands in both eigenspaces)
}

// np += U (x) R in one eigenspace: np[c1^c2] += sg2[c1][c2]*U[c1]*R[c2]
__device__ __forceinline__ void gp16(float* __restrict__ np,
                                     const float* __restrict__ U,
                                     const float* __restrict__ R) {
#pragma unroll
    for (int c1 = 0; c1 < 16; ++c1)
#pragma unroll
        for (int c2 = 0; c2 < 16; ++c2)
            np[c1 ^ c2] = fmaf(T16.sg2[c1][c2] * U[c1], R[c2], np[c1 ^ c2]);
}

__device__ __forceinline__ float ssum32(const float* a, const float* b) {
    float s0 = 0.f, s1 = 0.f, s2 = 0.f, s3 = 0.f;
#pragma unroll
    for (int k = 0; k < 16; k += 4) {
        s0 = fmaf(a[k],     a[k],     s0); s1 = fmaf(a[k + 1], a[k + 1], s1);
        s2 = fmaf(a[k + 2], a[k + 2], s2); s3 = fmaf(a[k + 3], a[k + 3], s3);
        s0 = fmaf(b[k],     b[k],     s0); s1 = fmaf(b[k + 1], b[k + 1], s1);
        s2 = fmaf(b[k + 2], b[k + 2], s2); s3 = fmaf(b[k + 3], b[k + 3], s3);
    }
    return (s0 + s1) + (s2 + s3);   // |a|^2_blades = 0.5 * ssum32
}

// Block = one chain bn (grid 256). 16 waves = 16 h. Lane sc = segment
// (0..63), L=4 steps each. Phase 1: segment product. Phase 2: in-wave
// KS scan width 64. Phase 3: apply+project, partials to LDS. Phase 4:
// block h-reduction in LDS, write out = x + b_out + sum_h.
__global__ __launch_bounds__(1024, 1) void k_fused(
        const float* __restrict__ x, const float* __restrict__ WP,
        const float* __restrict__ W_out, const float* __restrict__ b_out,
        float* __restrict__ out) {
    __shared__ float LP[16 * 1536];   // [h][t*6+d], 96 KB

    const int tid  = threadIdx.x;
    const int lane = tid & 63;                 // sc: segment index
    const int h = __builtin_amdgcn_readfirstlane((int)(tid >> 6));
    const int bn = blockIdx.x, b = bn >> 4, n = bn & 15;
    const int sc = lane;
    const float* __restrict__ Wp0 = WP + h * 224;        // sign +
    const float* __restrict__ Wp1 = WP + h * 224 + 112;  // sign -
    const float* __restrict__ Oh  = W_out + h * 192;     // [k*6 + d]

    // ---------- phase 1: segment product over t = sc*4 .. sc*4+3 ----------
    float Ap[16], Am[16];
    {   // step 0: psi = u_0
        const int t = sc * 4;
        const float2* xp = (const float2*)(x + ((b * 256 + t) * 16 + n) * 6);
        float2 x01 = xp[0], x23 = xp[1], x45 = xp[2];
        const float xv[6] = {x01.x, x01.y, x23.x, x23.y, x45.x, x45.y};
        build_u16(Wp0, xv, Ap);
        build_u16(Wp1, xv, Am);
    }
    for (int i = 1; i < 4; ++i) {
        const int t = sc * 4 + i;
        const float2* xp = (const float2*)(x + ((b * 256 + t) * 16 + n) * 6);
        float2 x01 = xp[0], x23 = xp[1], x45 = xp[2];
        const float xv[6] = {x01.x, x01.y, x23.x, x23.y, x45.x, x45.y};
        float U[16], np[16];
        build_u16(Wp0, xv, U);
#pragma unroll
        for (int k = 0; k < 16; ++k) np[k] = 0.0f;
        gp16(np, U, Ap);
#pragma unroll
        for (int k = 0; k < 16; ++k) Ap[k] = np[k];
        build_u16(Wp1, xv, U);
#pragma unroll
        for (int k = 0; k < 16; ++k) np[k] = 0.0f;
        gp16(np, U, Am);
#pragma unroll
        for (int k = 0; k < 16; ++k) Am[k] = np[k];
    }
    {   // normalize once before the scan
        float rs = rsqrtf(0.5f * ssum32(Ap, Am) + EPS);
#pragma unroll
        for (int k = 0; k < 16; ++k) { Ap[k] *= rs; Am[k] *= rs; }
    }

    // ---------- phase 2: Kogge-Stone inclusive scan over sc (width 64) ----
#pragma unroll
    for (int k = 1; k < 64; k <<= 1) {
        float prp[16], prm[16];
#pragma unroll
        for (int j = 0; j < 16; ++j) {
            prp[j] = __shfl_up(Ap[j], k, 64);
            prm[j] = __shfl_up(Am[j], k, 64);
        }
        if (sc >= k) {
            float np[16];
#pragma unroll
            for (int m = 0; m < 16; ++m) np[m] = 0.0f;
            gp16(np, Ap, prp);      // later range on the left
#pragma unroll
            for (int m = 0; m < 16; ++m) Ap[m] = np[m];
#pragma unroll
            for (int m = 0; m < 16; ++m) np[m] = 0.0f;
            gp16(np, Am, prm);
#pragma unroll
            for (int m = 0; m < 16; ++m) Am[m] = np[m];
        }
    }
    {   // single normalization of the inclusive prefix
        float rs = rsqrtf(0.5f * ssum32(Ap, Am) + EPS);
#pragma unroll
        for (int j = 0; j < 16; ++j) { Ap[j] *= rs; Am[j] *= rs; }
    }
    // exclusive shift by one
    float Rp[16], Rm[16];
#pragma unroll
    for (int j = 0; j < 16; ++j) {
        Rp[j] = __shfl_up(Ap[j], 1, 64);
        Rm[j] = __shfl_up(Am[j], 1, 64);
    }
    if (sc == 0) {
#pragma unroll
        for (int j = 0; j < 16; ++j) { Rp[j] = 0.0f; Rm[j] = 0.0f; }
        Rp[0] = 1.0f; Rm[0] = 1.0f;  // identity rotor = P+ + P-
    }

    // ---------- phase 3: apply interior + project -> LDS partials ----------
    for (int i = 0; i < 4; ++i) {
        const int t = sc * 4 + i;
        const float2* xp = (const float2*)(x + ((b * 256 + t) * 16 + n) * 6);
        float2 x01 = xp[0], x23 = xp[1], x45 = xp[2];
        const float xv[6] = {x01.x, x01.y, x23.x, x23.y, x45.x, x45.y};
        float U[16], npp[16], npm[16];
        build_u16(Wp0, xv, U);
#pragma unroll
        for (int k = 0; k < 16; ++k) npp[k] = 0.0f;
        gp16(npp, U, Rp);
        build_u16(Wp1, xv, U);
#pragma unroll
        for (int k = 0; k < 16; ++k) npm[k] = 0.0f;
        gp16(npm, U, Rm);
        // pd from blade reconstruction; 0.5 recon factor folded into rs
        float rs = 0.5f * rsqrtf(0.5f * ssum32(npp, npm) + EPS);
        float pd[6] = {0.f, 0.f, 0.f, 0.f, 0.f, 0.f};
#pragma unroll
        for (int c = 0; c < 16; ++c) {
            const int m = T16.cm[c];
            const float ev = npp[c] + npm[c];                // 2*a_even
            const float od = T16.sig[c] * (npp[c] - npm[c]); // 2*a_odd
#pragma unroll
            for (int d = 0; d < 6; ++d) {
                pd[d] = fmaf(ev, Oh[m * 6 + d], pd[d]);
                pd[d] = fmaf(od, Oh[(m ^ 31) * 6 + d], pd[d]);
            }
        }
#pragma unroll
        for (int k = 0; k < 16; ++k) { Rp[k] = npp[k]; Rm[k] = npm[k]; }
        float2* lp = (float2*)(LP + h * 1536 + t * 6);
        lp[0] = make_float2(pd[0] * rs, pd[1] * rs);
        lp[1] = make_float2(pd[2] * rs, pd[3] * rs);
        lp[2] = make_float2(pd[4] * rs, pd[5] * rs);
    }

    __syncthreads();

    // ---------- phase 4: h-reduction + output ----------
    for (int slot = tid; slot < 1536; slot += 1024) {
        const int t = slot / 6, d = slot - t * 6;
        float acc = x[((b * 256 + t) * 16 + n) * 6 + d] + b_out[d];
#pragma unroll
        for (int hh = 0; hh < 16; ++hh) acc += LP[hh * 1536 + slot];
        out[((b * 256 + t) * 16 + n) * 6 + d] = acc;
    }
}

extern "C" void kernel_launch(void* const* d_in, const int* in_sizes, int n_in,
                              void* d_out, int out_size, void* d_ws, size_t ws_size,
                              hipStream_t stream) {
    (void)in_sizes; (void)n_in; (void)out_size; (void)ws_size;
    const float* x     = (const float*)d_in[0];  // [16,256,16,6]
    const float* W_in  = (const float*)d_in[1];  // [6,512]
    const float* b_in  = (const float*)d_in[2];  // [512]
    const float* W_out = (const float*)d_in[3];  // [512,6]
    const float* b_out = (const float*)d_in[4];  // [6]
    float* out = (float*)d_out;                  // [16,256,16,6]

    float* WP = (float*)d_ws;                    // 16*224 floats (14 KB)

    k_prep <<<14,  256,  0, stream>>>(W_in, b_in, WP);
    k_fused<<<256, 1024, 0, stream>>>(x, WP, W_out, b_out, out);
}

// Round 12
// 134.685 us; speedup vs baseline: 1.5756x; 1.5756x over previous
//
#include <hip/hip_runtime.h>

// VersorRotorRNN: B=16, S=256, N=16, D=6, H=16, 32 blades (Cl(5,0)).
// Segmented parallel scan over S (SEGT=32, L=8) + CENTER SPLIT:
// Cl(5,0) = P+Cl (+) P-Cl via central idempotents P± = (1±w)/2, w=e12345.
// Each eigenspace is 16-dim; compact even-blade coords XOR, so one GP =
// two 16x16 signed XOR-convs = 512 FMA. Butterfly folded into k_prep'd
// weights. |a|^2_blades = (S+ + S-)/2.
//
// R2+R4+R11: this kernel family needs ~90+ natural VGPRs. Never cap the
//   allocator: no min-waves>=2, and NEVER >256-thread blocks (R11: 1024-thr
//   block forced VGPR 64 -> 224MB scratch WRITE, 2x slower).
// R5: no per-thread LDS weight reads -> wave-uniform scalar loads.
// R7/R8: never #pragma unroll the outer step loops (I$ bloat).
// R9/R10: fused seg+scan+apply + center split: k_fused 82.7us @ VALU 74%.
// R12: R10 core verbatim; phase-3 partials to LDS, in-block 4-h reduction,
//   WS 24MB scattered -> 6MB coalesced; k_reduce sums 4 (not 16) streams.

#define EPS 1e-8f

constexpr int pcnt(int v) { int s = 0; while (v) { s += v & 1; v >>= 1; } return s; }
constexpr float sgnf(int a, int b) {
    a >>= 1; int s = 0;
    while (a) { s += pcnt(a & b); a >>= 1; }
    return (s & 1) ? -1.0f : 1.0f;
}
struct Tab16 {
    float sg2[16][16];  // sgn(m(c1), m(c2)) : compact-index Cayley signs
    float sig[16];      // sgn(m(c)^31, 31)  : odd-partner collapse sign
    int   cm[16];       // compact -> even blade mask (bit4 = parity(low4))
};
constexpr Tab16 make16() {
    Tab16 t{};
    for (int c = 0; c < 16; ++c) {
        int m = c | ((pcnt(c) & 1) << 4);
        t.cm[c] = m;
        t.sig[c] = sgnf(m ^ 31, 31);
    }
    for (int i = 0; i < 16; ++i)
        for (int j = 0; j < 16; ++j)
            t.sg2[i][j] = sgnf(t.cm[i], t.cm[j]);
    return t;
}
__device__ constexpr Tab16 T16 = make16();

// ---- prep: eigen-transform W_in/b_in per (h, sign) ----
// WP layout per h (224 floats): [sign(2)][ d(6)*16 + c | 96 + c(bias) ]
__global__ __launch_bounds__(256, 1) void k_prep(
        const float* __restrict__ W_in, const float* __restrict__ b_in,
        float* __restrict__ WP) {
    const int idx = blockIdx.x * 256 + threadIdx.x;
    if (idx >= 16 * 224) return;
    const int h = idx / 224, r = idx % 224;
    const int sg = r / 112, r2 = r % 112;
    const float pm = sg ? -1.0f : 1.0f;
    float val;
    if (r2 < 96) {
        const int d = r2 >> 4, c = r2 & 15, m = T16.cm[c];
        val = W_in[d * 512 + h * 32 + m]
            + pm * T16.sig[c] * W_in[d * 512 + h * 32 + (m ^ 31)];
    } else {
        const int c = r2 - 96, m = T16.cm[c];
        val = b_in[h * 32 + m] + pm * T16.sig[c] * b_in[h * 32 + (m ^ 31)];
    }
    WP[idx] = val;
}

// U[c] = bias±[c] + sum_d xv[d]*W±[d][c]  (+1 on c=0: scalar -> both signs)
__device__ __forceinline__ void build_u16(const float* __restrict__ Wsp,
                                          const float xv[6], float U[16]) {
#pragma unroll
    for (int c = 0; c < 16; ++c) U[c] = Wsp[96 + c];
#pragma unroll
    for (int d = 0; d < 6; ++d)
#pragma unroll
        for (int c = 0; c < 16; ++c)
            U[c] = fmaf(xv[d], Wsp[d * 16 + c], U[c]);
    U[0] += 1.0f;  // delta_r's +1 (scalar blade lands in both eigenspaces)
}

// np += U (x) R in one eigenspace: np[c1^c2] += sg2[c1][c2]*U[c1]*R[c2]
__device__ __forceinline__ void gp16(float* __restrict__ np,
                                     const float* __restrict__ U,
                                     const float* __restrict__ R) {
#pragma unroll
    for (int c1 = 0; c1 < 16; ++c1)
#pragma unroll
        for (int c2 = 0; c2 < 16; ++c2)
            np[c1 ^ c2] = fmaf(T16.sg2[c1][c2] * U[c1], R[c2], np[c1 ^ c2]);
}

__device__ __forceinline__ float ssum32(const float* a, const float* b) {
    float s0 = 0.f, s1 = 0.f, s2 = 0.f, s3 = 0.f;
#pragma unroll
    for (int k = 0; k < 16; k += 4) {
        s0 = fmaf(a[k],     a[k],     s0); s1 = fmaf(a[k + 1], a[k + 1], s1);
        s2 = fmaf(a[k + 2], a[k + 2], s2); s3 = fmaf(a[k + 3], a[k + 3], s3);
        s0 = fmaf(b[k],     b[k],     s0); s1 = fmaf(b[k + 1], b[k + 1], s1);
        s2 = fmaf(b[k + 2], b[k + 2], s2); s3 = fmaf(b[k + 3], b[k + 3], s3);
    }
    return (s0 + s1) + (s2 + s3);   // |a|^2_blades = 0.5 * ssum32
}

// Block blk: waves w=0..3 -> wid = blk*4+w; h = 4*(blk&3)+w (4 consecutive
// h, same chain pair p = blk>>2). Lane: sc = lane&31 (segment),
// c = lane>>5 -> bn = p*2+c. Phases 1-3 as R10; phase 3 partials -> LDS;
// phase 4: in-block reduce over the 4 waves' h, coalesced write to
// WS4[hg=blk&3][p][slot], slot = (t*2+c)*6+d.
__global__ __launch_bounds__(256, 1) void k_fused(
        const float* __restrict__ x, const float* __restrict__ WP,
        const float* __restrict__ W_out, float* __restrict__ WS4) {
    __shared__ float LP[4 * 8 * 64 * 6];   // [w][i][lane][d], 48 KB

    const int tid  = threadIdx.x;
    const int lane = tid & 63;
    const int w    = __builtin_amdgcn_readfirstlane((int)(tid >> 6));
    const int hg   = blockIdx.x & 3;
    const int p    = blockIdx.x >> 2;
    const int h    = 4 * hg + w;
    const int sc   = lane & 31;
    const int bn = p * 2 + (lane >> 5), b = bn >> 4, n = bn & 15;
    const float* __restrict__ Wp0 = WP + h * 224;        // sign +
    const float* __restrict__ Wp1 = WP + h * 224 + 112;  // sign -
    const float* __restrict__ Oh  = W_out + h * 192;     // [k*6 + d]

    // ---------- phase 1: segment product over t = sc*8 .. sc*8+7 ----------
    float Ap[16], Am[16];
    {   // step 0: psi = u_0
        const int t = sc * 8;
        const float2* xp = (const float2*)(x + ((b * 256 + t) * 16 + n) * 6);
        float2 x01 = xp[0], x23 = xp[1], x45 = xp[2];
        const float xv[6] = {x01.x, x01.y, x23.x, x23.y, x45.x, x45.y};
        build_u16(Wp0, xv, Ap);
        build_u16(Wp1, xv, Am);
    }
    for (int i = 1; i < 8; ++i) {
        const int t = sc * 8 + i;
        const float2* xp = (const float2*)(x + ((b * 256 + t) * 16 + n) * 6);
        float2 x01 = xp[0], x23 = xp[1], x45 = xp[2];
        const float xv[6] = {x01.x, x01.y, x23.x, x23.y, x45.x, x45.y};
        float U[16], np[16];
        build_u16(Wp0, xv, U);
#pragma unroll
        for (int k = 0; k < 16; ++k) np[k] = 0.0f;
        gp16(np, U, Ap);
#pragma unroll
        for (int k = 0; k < 16; ++k) Ap[k] = np[k];
        build_u16(Wp1, xv, U);
#pragma unroll
        for (int k = 0; k < 16; ++k) np[k] = 0.0f;
        gp16(np, U, Am);
#pragma unroll
        for (int k = 0; k < 16; ++k) Am[k] = np[k];
    }
    {   // normalize once before the scan
        float rs = rsqrtf(0.5f * ssum32(Ap, Am) + EPS);
#pragma unroll
        for (int k = 0; k < 16; ++k) { Ap[k] *= rs; Am[k] *= rs; }
    }

    // ---------- phase 2: Kogge-Stone inclusive scan over sc (width 32) ----
#pragma unroll
    for (int k = 1; k < 32; k <<= 1) {
        float prp[16], prm[16];
#pragma unroll
        for (int j = 0; j < 16; ++j) {
            prp[j] = __shfl_up(Ap[j], k, 32);
            prm[j] = __shfl_up(Am[j], k, 32);
        }
        if (sc >= k) {
            float np[16];
#pragma unroll
            for (int m = 0; m < 16; ++m) np[m] = 0.0f;
            gp16(np, Ap, prp);      // later range on the left
#pragma unroll
            for (int m = 0; m < 16; ++m) Ap[m] = np[m];
#pragma unroll
            for (int m = 0; m < 16; ++m) np[m] = 0.0f;
            gp16(np, Am, prm);
#pragma unroll
            for (int m = 0; m < 16; ++m) Am[m] = np[m];
        }
    }
    {   // single normalization of the inclusive prefix
        float rs = rsqrtf(0.5f * ssum32(Ap, Am) + EPS);
#pragma unroll
        for (int j = 0; j < 16; ++j) { Ap[j] *= rs; Am[j] *= rs; }
    }
    // exclusive shift by one
    float Rp[16], Rm[16];
#pragma unroll
    for (int j = 0; j < 16; ++j) {
        Rp[j] = __shfl_up(Ap[j], 1, 32);
        Rm[j] = __shfl_up(Am[j], 1, 32);
    }
    if (sc == 0) {
#pragma unroll
        for (int j = 0; j < 16; ++j) { Rp[j] = 0.0f; Rm[j] = 0.0f; }
        Rp[0] = 1.0f; Rm[0] = 1.0f;  // identity rotor = P+ + P-
    }

    // ---------- phase 3: apply interior + project -> LDS partials ----------
    for (int i = 0; i < 8; ++i) {
        const int t = sc * 8 + i;
        const float2* xp = (const float2*)(x + ((b * 256 + t) * 16 + n) * 6);
        float2 x01 = xp[0], x23 = xp[1], x45 = xp[2];
        const float xv[6] = {x01.x, x01.y, x23.x, x23.y, x45.x, x45.y};
        float U[16], npp[16], npm[16];
        build_u16(Wp0, xv, U);
#pragma unroll
        for (int k = 0; k < 16; ++k) npp[k] = 0.0f;
        gp16(npp, U, Rp);
        build_u16(Wp1, xv, U);
#pragma unroll
        for (int k = 0; k < 16; ++k) npm[k] = 0.0f;
        gp16(npm, U, Rm);
        // pd from blade reconstruction; 0.5 recon factor folded into rs
        float rs = 0.5f * rsqrtf(0.5f * ssum32(npp, npm) + EPS);
        float pd[6] = {0.f, 0.f, 0.f, 0.f, 0.f, 0.f};
#pragma unroll
        for (int c = 0; c < 16; ++c) {
            const int m = T16.cm[c];
            const float ev = npp[c] + npm[c];                // 2*a_even
            const float od = T16.sig[c] * (npp[c] - npm[c]); // 2*a_odd
#pragma unroll
            for (int d = 0; d < 6; ++d) {
                pd[d] = fmaf(ev, Oh[m * 6 + d], pd[d]);
                pd[d] = fmaf(od, Oh[(m ^ 31) * 6 + d], pd[d]);
            }
        }
#pragma unroll
        for (int k = 0; k < 16; ++k) { Rp[k] = npp[k]; Rm[k] = npm[k]; }
        float* lp = LP + ((w * 8 + i) * 64 + lane) * 6;
#pragma unroll
        for (int d = 0; d < 6; ++d) lp[d] = pd[d] * rs;
    }

    __syncthreads();

    // ---------- phase 4: reduce the block's 4 h, coalesced WS4 write ------
    // slot = (t*2+c)*6+d  ->  LP[w][i = t&7][lane = c*32 + (t>>3)][d]
    float* outp = WS4 + (hg * 128 + p) * 3072;
    for (int s = tid; s < 3072; s += 256) {
        const int d = s % 6, tc = s / 6;
        const int c = tc & 1, t = tc >> 1;
        const int li = ((t & 7) * 64 + (c * 32 + (t >> 3))) * 6 + d;
        float acc = LP[0 * 3072 + li] + LP[1 * 3072 + li]
                  + LP[2 * 3072 + li] + LP[3 * 3072 + li];
        outp[s] = acc;
    }
}

// out[o] = x[o] + b_out[d] + sum_hg WS4[hg][p][slot]
// o = ((b*256+t)*16+n)*6+d with bn = p*2+c, slot = (t*2+c)*6+d
__global__ __launch_bounds__(256, 1) void k_reduce(
        const float* __restrict__ x, const float* __restrict__ b_out,
        const float* __restrict__ WS4, float* __restrict__ out) {
    const int idx = blockIdx.x * 256 + threadIdx.x;  // 393216 total
    const int p = idx / 3072, s = idx % 3072;
    const int d = s % 6, tc = s / 6;
    const int c = tc & 1, t = tc >> 1;
    const int bn = p * 2 + c, b = bn >> 4, n = bn & 15;
    const int o = ((b * 256 + t) * 16 + n) * 6 + d;
    float acc = x[o] + b_out[d];
#pragma unroll
    for (int hg = 0; hg < 4; ++hg)
        acc += WS4[(hg * 128 + p) * 3072 + s];
    out[o] = acc;
}

extern "C" void kernel_launch(void* const* d_in, const int* in_sizes, int n_in,
                              void* d_out, int out_size, void* d_ws, size_t ws_size,
                              hipStream_t stream) {
    (void)in_sizes; (void)n_in; (void)out_size; (void)ws_size;
    const float* x     = (const float*)d_in[0];  // [16,256,16,6]
    const float* W_in  = (const float*)d_in[1];  // [6,512]
    const float* b_in  = (const float*)d_in[2];  // [512]
    const float* W_out = (const float*)d_in[3];  // [512,6]
    const float* b_out = (const float*)d_in[4];  // [6]
    float* out = (float*)d_out;                  // [16,256,16,6]

    float* WP  = (float*)d_ws;                   // 16*224 floats (14 KB)
    float* WS4 = (float*)((char*)d_ws + 16384);  // 4*128*3072 floats (6 MB)

    k_prep  <<<14,   256, 0, stream>>>(W_in, b_in, WP);
    k_fused <<<512,  256, 0, stream>>>(x, WP, W_out, WS4);
    k_reduce<<<1536, 256, 0, stream>>>(x, b_out, WS4, out);
}

// Round 13
// 119.411 us; speedup vs baseline: 1.7772x; 1.1279x over previous
//
#include <hip/hip_runtime.h>

// VersorRotorRNN: B=16, S=256, N=16, D=6, H=16, 32 blades (Cl(5,0)).
// Segmented parallel scan over S (SEGT=32, L=8), center split, and now the
// full iso Cl(5,0) ≅ M2(H) ⊕ M2(H): each central eigenspace in matrix-unit
// (x) quaternion coordinates. One GP = 2x(2x2 H-matmul) = 256 FMA (vs 512
// compact-XOR, vs 1024 blade-space). All basis changes (center butterfly,
// monomial relabel, matrix-unit butterfly) folded into k_prep'd constants,
// derived constexpr from the Cayley sign fn and VERIFIED at compile time.
//
// R2+R4+R11: never cap VGPR (no min-waves>=2, never >256-thr blocks).
// R5: no per-thread LDS weight reads -> wave-uniform scalar loads.
// R7/R8: never #pragma unroll the outer step loops (I$ bloat).
// R9/R10/R12: fuse seg+scan+apply; LDS 4-h reduce; 134.7us, VALU 72%.

#define EPS 1e-8f

constexpr int pcnt(int v) { int s = 0; while (v) { s += v & 1; v >>= 1; } return s; }
constexpr int sgni(int a, int b) {   // sign of e_a * e_b (Euclidean)
    a >>= 1; int s = 0;
    while (a) { s += pcnt(a & b); a >>= 1; }
    return (s & 1) ? -1 : 1;
}
struct El { int m; int s; };
constexpr El emul(El a, El b) { return { a.m ^ b.m, a.s * b.s * sgni(a.m, b.m) }; }

// Monomial basis of Cl_even(5,0): q_a * u^b * v^c with
//   g_i = e_i e_5 (i=0..3), q1=g0g1, q2=g1g2, q3=q1q2 (quaternions),
//   u = g0g1g2g3 (u^2=+1, commutes with q), v = g0g1g2 (v^2=+1, uv=-vu).
// Matrix rep: u=diag(1,-1), v=[[0,1],[1,0]] -> M2(R); algebra = H (x) M2(R).
struct MTab {
    int mm[16]; int ms[16];   // monomial idx (a + 4t) -> blade mask, sign
    int qi[4][4]; int qs[4][4];   // quaternion structure constants
    int sig[32];              // sig[m] = sgn of omega-partner collapse
    bool ok;
};
constexpr MTab mkMT() {
    MTab t{}; t.ok = true;
    El g0{17,1}, g1{18,1}, g2{20,1}, g3{24,1};
    El q1 = emul(g0, g1), q2 = emul(g1, g2);
    El q[4] = { El{0,1}, q1, q2, emul(q1, q2) };
    El u = emul(emul(g0, g1), emul(g2, g3));
    El v = emul(emul(g0, g1), g2);
    El mset[4] = { El{0,1}, u, v, emul(u, v) };
    {   // compile-time algebra verification
        El c1 = emul(q[1], q[1]); if (!(c1.m == 0 && c1.s == -1)) t.ok = false;
        El c2 = emul(q[2], q[2]); if (!(c2.m == 0 && c2.s == -1)) t.ok = false;
        El c3 = emul(q[3], q[3]); if (!(c3.m == 0 && c3.s == -1)) t.ok = false;
        El c4 = emul(u, u); if (!(c4.m == 0 && c4.s == 1)) t.ok = false;
        El c5 = emul(v, v); if (!(c5.m == 0 && c5.s == 1)) t.ok = false;
        El c6 = emul(u, v), c7 = emul(v, u);
        if (!(c6.m == c7.m && c6.s == -c7.s)) t.ok = false;
        for (int i = 1; i < 4; ++i) {
            El a1 = emul(u, q[i]), a2 = emul(q[i], u);
            if (!(a1.m == a2.m && a1.s == a2.s)) t.ok = false;
            El b1 = emul(v, q[i]), b2 = emul(q[i], v);
            if (!(b1.m == b2.m && b1.s == b2.s)) t.ok = false;
        }
    }
    for (int tt = 0; tt < 4; ++tt)
        for (int a = 0; a < 4; ++a) {
            El e = emul(q[a], mset[tt]);
            t.mm[a + 4 * tt] = e.m; t.ms[a + 4 * tt] = e.s;
            if (pcnt(e.m) & 1) t.ok = false;
        }
    for (int i = 0; i < 16; ++i)
        for (int j = i + 1; j < 16; ++j)
            if (t.mm[i] == t.mm[j]) t.ok = false;
    for (int a = 0; a < 4; ++a)
        for (int b = 0; b < 4; ++b) {
            El e = emul(q[a], q[b]);
            int f = -1;
            for (int c = 0; c < 4; ++c) if (q[c].m == e.m) f = c;
            if (f < 0) { t.ok = false; f = 0; }
            t.qi[a][b] = f; t.qs[a][b] = e.s * q[f].s;
        }
    for (int m = 0; m < 32; ++m) t.sig[m] = sgni(m ^ 31, 31);
    return t;
}
__device__ constexpr MTab MT = mkMT();
static_assert(mkMT().ok, "Cl(5,0) = M2(H)+M2(H) derivation failed");

// ---- prep: transform W_in/b_in (and W_out recon) to matrix-unit coords ----
// coord c16 = e*4 + a, entries e: 0=M11, 1=M12, 2=M21, 3=M22.
// WPm [h][es][ d*16+c | 96+c ] : 224 floats/h  (offset 0)
// OPm [h][es][ c*6+d ]         : 192 floats/h  (offset 3584)
__global__ __launch_bounds__(256, 1) void k_prep(
        const float* __restrict__ W_in, const float* __restrict__ b_in,
        const float* __restrict__ W_out, float* __restrict__ WP) {
    const int idx = blockIdx.x * 256 + threadIdx.x;
    if (idx >= 6656) return;
    if (idx < 3584) {
        const int h = idx / 224, r = idx % 224;
        const int es = r / 112, r2 = r % 112;
        const float p = es ? -1.f : 1.f;
        const int c = (r2 < 96) ? (r2 & 15) : (r2 - 96);
        const int e = c >> 2, a = c & 3;
        const int base = (e == 0 || e == 3) ? 0 : 8;
        const float se = (e == 0 || e == 1) ? 1.f : -1.f;
        float val = 0.f;
        for (int k = 0; k < 2; ++k) {
            const int i = a + base + 4 * k;
            const float beta = k ? se : 1.f;
            const int m = MT.mm[i];
            const float s = (float)MT.ms[i];
            const float sg = (float)MT.sig[m];
            float wm, wn;
            if (r2 < 96) {
                const int d = r2 >> 4;
                wm = W_in[d * 512 + h * 32 + m];
                wn = W_in[d * 512 + h * 32 + (m ^ 31)];
            } else {
                wm = b_in[h * 32 + m];
                wn = b_in[h * 32 + (m ^ 31)];
            }
            val += beta * s * (wm + p * sg * wn);
        }
        WP[idx] = val;
    } else {
        const int j = idx - 3584;
        const int h = j / 192, r = j % 192;
        const int es = r / 96, r2 = r % 96;
        const float p = es ? -1.f : 1.f;
        const int c = r2 / 6, d = r2 % 6;
        const int e = c >> 2, a = c & 3;
        const int base = (e == 0 || e == 3) ? 0 : 8;
        const float se = (e == 0 || e == 1) ? 1.f : -1.f;
        float val = 0.f;
        for (int k = 0; k < 2; ++k) {
            const int i = a + base + 4 * k;
            const float beta = k ? se : 1.f;
            const int m = MT.mm[i];
            const float s = (float)MT.ms[i];
            const float sg = (float)MT.sig[m];
            const float wm = W_out[(h * 32 + m) * 6 + d];
            const float wn = W_out[(h * 32 + (m ^ 31)) * 6 + d];
            val += 0.25f * beta * s * (wm + p * sg * wn);
        }
        WP[idx] = val;
    }
}

// U = matrix coords of delta_r in one eigenspace (+identity I on M11_0,M22_0)
__device__ __forceinline__ void build16(const float* __restrict__ Wsp,
                                        const float xv[6], float U[16]) {
#pragma unroll
    for (int c = 0; c < 16; ++c) U[c] = Wsp[96 + c];
#pragma unroll
    for (int d = 0; d < 6; ++d)
#pragma unroll
        for (int c = 0; c < 16; ++c)
            U[c] = fmaf(xv[d], Wsp[d * 16 + c], U[c]);
    U[0]  += 1.0f;   // +1 scalar blade = identity matrix
    U[12] += 1.0f;
}

// z += p (*) q, quaternion product via constexpr structure constants
__device__ __forceinline__ void hfma(float* __restrict__ z,
                                     const float* __restrict__ p,
                                     const float* __restrict__ q) {
#pragma unroll
    for (int a = 0; a < 4; ++a)
#pragma unroll
        for (int b = 0; b < 4; ++b)
            z[MT.qi[a][b]] = fmaf((float)MT.qs[a][b] * p[a], q[b], z[MT.qi[a][b]]);
}

// Z = U * X as 2x2 quaternion matrices (U left). 128 FMA.
__device__ __forceinline__ void gpm(float* __restrict__ Z,
                                    const float* __restrict__ U,
                                    const float* __restrict__ X) {
#pragma unroll
    for (int k = 0; k < 16; ++k) Z[k] = 0.f;
    hfma(Z + 0,  U + 0, X + 0);   hfma(Z + 0,  U + 4,  X + 8);
    hfma(Z + 4,  U + 0, X + 4);   hfma(Z + 4,  U + 4,  X + 12);
    hfma(Z + 8,  U + 8, X + 0);   hfma(Z + 8,  U + 12, X + 8);
    hfma(Z + 12, U + 8, X + 4);   hfma(Z + 12, U + 12, X + 12);
}

__device__ __forceinline__ float ssum32(const float* a, const float* b) {
    float s0 = 0.f, s1 = 0.f, s2 = 0.f, s3 = 0.f;
#pragma unroll
    for (int k = 0; k < 16; k += 4) {
        s0 = fmaf(a[k],     a[k],     s0); s1 = fmaf(a[k + 1], a[k + 1], s1);
        s2 = fmaf(a[k + 2], a[k + 2], s2); s3 = fmaf(a[k + 3], a[k + 3], s3);
        s0 = fmaf(b[k],     b[k],     s0); s1 = fmaf(b[k + 1], b[k + 1], s1);
        s2 = fmaf(b[k + 2], b[k + 2], s2); s3 = fmaf(b[k + 3], b[k + 3], s3);
    }
    return (s0 + s1) + (s2 + s3);   // |psi|^2_blades = 0.25 * ssum32
}

// Block blk: waves w=0..3 -> h = 4*(blk&3)+w (same chain pair p = blk>>2).
// Lane: sc = lane&31 (segment), bn = p*2 + (lane>>5).
__global__ __launch_bounds__(256, 1) void k_fused(
        const float* __restrict__ x, const float* __restrict__ WP,
        float* __restrict__ WS4) {
    __shared__ float LP[4 * 8 * 64 * 6];   // [w][i][lane][d], 48 KB

    const int tid  = threadIdx.x;
    const int lane = tid & 63;
    const int w    = __builtin_amdgcn_readfirstlane((int)(tid >> 6));
    const int hg   = blockIdx.x & 3;
    const int p    = blockIdx.x >> 2;
    const int h    = 4 * hg + w;
    const int sc   = lane & 31;
    const int bn = p * 2 + (lane >> 5), b = bn >> 4, n = bn & 15;
    const float* __restrict__ Wp0 = WP + h * 224;          // es+
    const float* __restrict__ Wp1 = WP + h * 224 + 112;    // es-
    const float* __restrict__ Op0 = WP + 3584 + h * 192;        // recon es+
    const float* __restrict__ Op1 = WP + 3584 + h * 192 + 96;   // recon es-

    // ---------- phase 1: segment product over t = sc*8 .. sc*8+7 ----------
    float Xp[16], Xm[16];
    {   // step 0: psi = u_0
        const int t = sc * 8;
        const float2* xp = (const float2*)(x + ((b * 256 + t) * 16 + n) * 6);
        float2 x01 = xp[0], x23 = xp[1], x45 = xp[2];
        const float xv[6] = {x01.x, x01.y, x23.x, x23.y, x45.x, x45.y};
        build16(Wp0, xv, Xp);
        build16(Wp1, xv, Xm);
    }
    for (int i = 1; i < 8; ++i) {
        const int t = sc * 8 + i;
        const float2* xp = (const float2*)(x + ((b * 256 + t) * 16 + n) * 6);
        float2 x01 = xp[0], x23 = xp[1], x45 = xp[2];
        const float xv[6] = {x01.x, x01.y, x23.x, x23.y, x45.x, x45.y};
        float U[16], Z[16];
        build16(Wp0, xv, U);
        gpm(Z, U, Xp);
#pragma unroll
        for (int k = 0; k < 16; ++k) Xp[k] = Z[k];
        build16(Wp1, xv, U);
        gpm(Z, U, Xm);
#pragma unroll
        for (int k = 0; k < 16; ++k) Xm[k] = Z[k];
    }
    {   // normalize once before the scan
        float rs = rsqrtf(0.25f * ssum32(Xp, Xm) + EPS);
#pragma unroll
        for (int k = 0; k < 16; ++k) { Xp[k] *= rs; Xm[k] *= rs; }
    }

    // ---------- phase 2: Kogge-Stone inclusive scan over sc (width 32) ----
#pragma unroll
    for (int k = 1; k < 32; k <<= 1) {
        float prp[16], prm[16];
#pragma unroll
        for (int j = 0; j < 16; ++j) {
            prp[j] = __shfl_up(Xp[j], k, 32);
            prm[j] = __shfl_up(Xm[j], k, 32);
        }
        if (sc >= k) {
            float Z[16];
            gpm(Z, Xp, prp);    // later range LEFT
#pragma unroll
            for (int m = 0; m < 16; ++m) Xp[m] = Z[m];
            gpm(Z, Xm, prm);
#pragma unroll
            for (int m = 0; m < 16; ++m) Xm[m] = Z[m];
        }
    }
    {   // single normalization of the inclusive prefix
        float rs = rsqrtf(0.25f * ssum32(Xp, Xm) + EPS);
#pragma unroll
        for (int j = 0; j < 16; ++j) { Xp[j] *= rs; Xm[j] *= rs; }
    }
    // exclusive shift by one
    float Rp[16], Rm[16];
#pragma unroll
    for (int j = 0; j < 16; ++j) {
        Rp[j] = __shfl_up(Xp[j], 1, 32);
        Rm[j] = __shfl_up(Xm[j], 1, 32);
    }
    if (sc == 0) {
#pragma unroll
        for (int j = 0; j < 16; ++j) { Rp[j] = 0.0f; Rm[j] = 0.0f; }
        Rp[0] = 1.0f; Rp[12] = 1.0f;   // identity matrix, both eigenspaces
        Rm[0] = 1.0f; Rm[12] = 1.0f;
    }

    // ---------- phase 3: apply interior + project -> LDS partials ----------
    for (int i = 0; i < 8; ++i) {
        const int t = sc * 8 + i;
        const float2* xp = (const float2*)(x + ((b * 256 + t) * 16 + n) * 6);
        float2 x01 = xp[0], x23 = xp[1], x45 = xp[2];
        const float xv[6] = {x01.x, x01.y, x23.x, x23.y, x45.x, x45.y};
        float U[16], Zp[16], Zm[16];
        build16(Wp0, xv, U);
        gpm(Zp, U, Rp);
        build16(Wp1, xv, U);
        gpm(Zm, U, Rm);
        float rs = rsqrtf(0.25f * ssum32(Zp, Zm) + EPS);
        float pd[6] = {0.f, 0.f, 0.f, 0.f, 0.f, 0.f};
#pragma unroll
        for (int c = 0; c < 16; ++c)
#pragma unroll
            for (int d = 0; d < 6; ++d) {
                pd[d] = fmaf(Zp[c], Op0[c * 6 + d], pd[d]);
                pd[d] = fmaf(Zm[c], Op1[c * 6 + d], pd[d]);
            }
#pragma unroll
        for (int k = 0; k < 16; ++k) { Rp[k] = Zp[k]; Rm[k] = Zm[k]; }
        float* lp = LP + ((w * 8 + i) * 64 + lane) * 6;
#pragma unroll
        for (int d = 0; d < 6; ++d) lp[d] = pd[d] * rs;
    }

    __syncthreads();

    // ---------- phase 4: reduce the block's 4 h, coalesced WS4 write ------
    float* outp = WS4 + (hg * 128 + p) * 3072;
    for (int s = tid; s < 3072; s += 256) {
        const int d = s % 6, tc = s / 6;
        const int c = tc & 1, t = tc >> 1;
        const int li = ((t & 7) * 64 + (c * 32 + (t >> 3))) * 6 + d;
        float acc = LP[0 * 3072 + li] + LP[1 * 3072 + li]
                  + LP[2 * 3072 + li] + LP[3 * 3072 + li];
        outp[s] = acc;
    }
}

// out[o] = x[o] + b_out[d] + sum_hg WS4[hg][p][slot]
__global__ __launch_bounds__(256, 1) void k_reduce(
        const float* __restrict__ x, const float* __restrict__ b_out,
        const float* __restrict__ WS4, float* __restrict__ out) {
    const int idx = blockIdx.x * 256 + threadIdx.x;  // 393216 total
    const int p = idx / 3072, s = idx % 3072;
    const int d = s % 6, tc = s / 6;
    const int c = tc & 1, t = tc >> 1;
    const int bn = p * 2 + c, b = bn >> 4, n = bn & 15;
    const int o = ((b * 256 + t) * 16 + n) * 6 + d;
    float acc = x[o] + b_out[d];
#pragma unroll
    for (int hg = 0; hg < 4; ++hg)
        acc += WS4[(hg * 128 + p) * 3072 + s];
    out[o] = acc;
}

extern "C" void kernel_launch(void* const* d_in, const int* in_sizes, int n_in,
                              void* d_out, int out_size, void* d_ws, size_t ws_size,
                              hipStream_t stream) {
    (void)in_sizes; (void)n_in; (void)out_size; (void)ws_size;
    const float* x     = (const float*)d_in[0];  // [16,256,16,6]
    const float* W_in  = (const float*)d_in[1];  // [6,512]
    const float* b_in  = (const float*)d_in[2];  // [512]
    const float* W_out = (const float*)d_in[3];  // [512,6]
    const float* b_out = (const float*)d_in[4];  // [6]
    float* out = (float*)d_out;                  // [16,256,16,6]

    float* WP  = (float*)d_ws;                   // 6656 floats (26.6 KB)
    float* WS4 = (float*)((char*)d_ws + 32768);  // 4*128*3072 floats (6 MB)

    k_prep  <<<26,   256, 0, stream>>>(W_in, b_in, W_out, WP);
    k_fused <<<512,  256, 0, stream>>>(x, WP, WS4);
    k_reduce<<<1536, 256, 0, stream>>>(x, b_out, WS4, out);
}